// Round 5
// baseline (983.373 us; speedup 1.0000x reference)
//
#include <hip/hip_runtime.h>
#include <math.h>

// ---------------- weight transpose: w[18][C][3][3] -> wt[C][9][18] ----------------
__global__ void transpose_w_kernel(const float* __restrict__ w, float* __restrict__ wt, int C) {
  int idx = blockIdx.x * blockDim.x + threadIdx.x;
  int total = 18 * C * 9;
  if (idx >= total) return;
  int co = idx / (C * 9);
  int rem = idx % (C * 9);
  int ci = rem / 9;
  int tap = rem % 9;
  wt[(ci * 9 + tap) * 18 + co] = w[idx];
}

// ---------------- fc1 transpose: fc1_w[225][450] -> wt[450][256] (padded) ----------------
__global__ void transpose_fc1_kernel(const float* __restrict__ w, float* __restrict__ wt) {
  int idx = blockIdx.x * blockDim.x + threadIdx.x;
  if (idx >= 225 * 450) return;
  int o = idx / 450;
  int i = idx % 450;
  wt[i * 256 + o] = w[idx];
}

// ------------- fused conv3x3 + BN + relu + conv1x1 -------------
// 512 threads = 64 pixels x 8 channel-splits (8 waves/block -> occupancy cap),
// register A/B double-buffer on the 9 input taps to pipeline load vs FMA.
template <int CIN_SPLIT>
__global__ __launch_bounds__(512) void pre_kernel(
    const float* __restrict__ x, const float* __restrict__ wt,
    const float* __restrict__ b1, const float* __restrict__ gamma,
    const float* __restrict__ beta, const float* __restrict__ mean,
    const float* __restrict__ var, const float* __restrict__ w2,
    const float* __restrict__ b2, float* __restrict__ out, int H, int W) {
  constexpr int NSPLIT = 8;
  int tid = threadIdx.x;
  int pixel = tid & 63;
  int split = __builtin_amdgcn_readfirstlane(tid >> 6);  // wave-uniform -> SGPR
  int w = blockIdx.x * 64 + pixel;
  int h = blockIdx.y;
  int b = blockIdx.z;
  bool active = (w < W);

  float acc[18];
#pragma unroll
  for (int i = 0; i < 18; i++) acc[i] = 0.f;

  const float* xb = x + (size_t)b * (CIN_SPLIT * NSPLIT) * H * W;
  int ci0 = split * CIN_SPLIT;

  auto load9 = [&](int ci, float (&dst)[9]) {
    const float* plane = xb + (size_t)(ci0 + ci) * H * W;
#pragma unroll
    for (int dh = 0; dh < 3; dh++) {
      int r = h + dh - 1;
      bool rv = ((unsigned)r < (unsigned)H) && active;
      const float* row = plane + (size_t)r * W;
      dst[dh * 3 + 0] = (rv && w >= 1) ? row[w - 1] : 0.f;
      dst[dh * 3 + 1] = rv ? row[w] : 0.f;
      dst[dh * 3 + 2] = (rv && w + 1 < W) ? row[w + 1] : 0.f;
    }
  };
  auto fma9 = [&](int ci, const float (&v)[9]) {
    const float* wp = wt + (size_t)(ci0 + ci) * 9 * 18;  // scalar addr chain
#pragma unroll
    for (int tap = 0; tap < 9; tap++)
#pragma unroll
      for (int co = 0; co < 18; co++)
        acc[co] = fmaf(v[tap], wp[tap * 18 + co], acc[co]);
  };

  float A[9], B[9];
  load9(0, A);
  for (int ci = 0; ci < CIN_SPLIT; ci += 2) {
    load9(ci + 1, B);   // prefetch ci+1 while ci's FMAs run
    fma9(ci, A);
    if (ci + 2 < CIN_SPLIT) load9(ci + 2, A);
    fma9(ci + 1, B);
  }

  __shared__ float red[NSPLIT - 1][64][19];  // pad 19: stride-19 mod 32 conflict-free
  if (split > 0) {
#pragma unroll
    for (int co = 0; co < 18; co++) red[split - 1][pixel][co] = acc[co];
  }
  __syncthreads();
  if (split == 0 && active) {
#pragma unroll
    for (int s = 0; s < NSPLIT - 1; s++)
#pragma unroll
      for (int co = 0; co < 18; co++) acc[co] += red[s][pixel][co];
    float y[18];
#pragma unroll
    for (int co = 0; co < 18; co++) {
      float sc = gamma[co] / sqrtf(var[co] + 1e-3f);
      y[co] = fmaxf((acc[co] + b1[co] - mean[co]) * sc + beta[co], 0.f);
    }
    size_t obase = (size_t)b * 18 * H * W + (size_t)h * W + w;
#pragma unroll
    for (int co2 = 0; co2 < 18; co2++) {
      float s2 = b2[co2];
#pragma unroll
      for (int c = 0; c < 18; c++) s2 = fmaf(y[c], w2[co2 * 18 + c], s2);
      out[obase + (size_t)co2 * H * W] = s2;
    }
  }
}

// ------------- per-ROI classifier: one 256-thread block (4 waves) per ROI -------------
__global__ __launch_bounds__(256) void classifier_kernel(
    const float* __restrict__ ffv, const float* __restrict__ fbev,
    const float* __restrict__ rois, const float* __restrict__ Wq,
    const float* __restrict__ bq, const float* __restrict__ Wk,
    const float* __restrict__ bk, const float* __restrict__ Wv,
    const float* __restrict__ bv, const float* __restrict__ Wf,
    const float* __restrict__ bf, const float* __restrict__ conv_w,
    const float* __restrict__ conv_b, const float* __restrict__ wt_fc1,
    const float* __restrict__ fc1_b, const float* __restrict__ fc2_w,
    const float* __restrict__ fc2_b, float* __restrict__ out) {
  int rid = blockIdx.x;
  int b = rid >> 10;
  int tid = threadIdx.x;

  __shared__ float sW[2500];           // Wq | Wk | Wv | Wf (625 each)
  __shared__ float sB[100];            // bq | bk | bv | bf (25 each)
  __shared__ float sfv[450], sbev[450];
  __shared__ float pr[6][450];         // qf kf vf qb kb vb
  __shared__ float av[2][450];
  __shared__ float xx[2][450];
  __shared__ float hid[450];
  __shared__ float h1r[225];
  __shared__ float lg[3];
  __shared__ int c_ixf[25], c_iyf[25], c_vf[25];
  __shared__ int c_ixb[25], c_iyb[25], c_vb[25];

  // ---- stage projection weights + biases into LDS ----
  for (int t = tid; t < 625; t += 256) {
    sW[t] = Wq[t];
    sW[625 + t] = Wk[t];
    sW[1250 + t] = Wv[t];
    sW[1875 + t] = Wf[t];
  }
  if (tid < 25) {
    sB[tid] = bq[tid];
    sB[25 + tid] = bk[tid];
    sB[50 + tid] = bv[tid];
    sB[75 + tid] = bf[tid];
  }

  // ---- box + grids coords (double to match np f64 ref) ----
  if (tid < 25) {
    const float* roi = rois + (size_t)rid * 7;
    double x0 = roi[0], y0 = roi[1], z0 = roi[2];
    double dx = roi[3], dy = roi[4], dz = roi[5], th = roi[6];
    double c = cos(th), s = sin(th);
    double half1 = (dy * c + dx * s) / 2.0;
    double half2 = (dy * s + dx * c) / 2.0;
    double bx1 = x0 - half1, bx2 = x0 + half1;
    double by1 = y0 - half2, by2 = y0 + half2;
    double bz1 = z0 - dz / 2.0, bz2 = z0 + dz / 2.0;
    int i = tid / 5, j = tid % 5;
    double ti = i * 0.25, tj = j * 0.25;
    // fv: feat (18, 64, 512)
    double gz = bz1 + ti * (bz2 - bz1);
    gz = (gz + 1.0) / 2.0;
    double gx = bx1 + tj * (bx2 - bx1);
    gx = (gx - 35.2) / 35.2;
    double ixf = rint((gz + 1.0) * 0.5 * 511.0);
    double iyf = rint((gx + 1.0) * 0.5 * 63.0);
    c_vf[tid] = (ixf >= 0.0) && (ixf <= 511.0) && (iyf >= 0.0) && (iyf <= 63.0);
    c_ixf[tid] = (int)fmin(fmax(ixf, 0.0), 511.0);
    c_iyf[tid] = (int)fmin(fmax(iyf, 0.0), 63.0);
    // bev: feat (18, 200, 176)
    double gzb = (by1 + ti * (by2 - by1)) / 40.0;
    double ixb = rint((gzb + 1.0) * 0.5 * 175.0);
    double iyb = rint((gx + 1.0) * 0.5 * 199.0);
    c_vb[tid] = (ixb >= 0.0) && (ixb <= 175.0) && (iyb >= 0.0) && (iyb <= 199.0);
    c_ixb[tid] = (int)fmin(fmax(ixb, 0.0), 175.0);
    c_iyb[tid] = (int)fmin(fmax(iyb, 0.0), 199.0);
  }
  __syncthreads();

  // ---- gather: 900 items (450 fv + 450 bev) across 256 threads ----
  {
    const float* fvb = ffv + (size_t)b * 18 * 64 * 512;
    const float* bvb = fbev + (size_t)b * 18 * 200 * 176;
    for (int item = tid; item < 900; item += 256) {
      if (item < 450) {
        int ch = item / 25, pos = item % 25;
        sfv[item] = c_vf[pos] ? fvb[((size_t)ch * 64 + c_iyf[pos]) * 512 + c_ixf[pos]] : 0.f;
      } else {
        int it = item - 450;
        int ch = it / 25, pos = it % 25;
        sbev[it] = c_vb[pos] ? bvb[((size_t)ch * 200 + c_iyb[pos]) * 176 + c_ixb[pos]] : 0.f;
      }
    }
  }
  __syncthreads();

  // ---- 6 projections: {fv,bev} x {Wq,Wk,Wv} (weights from LDS) ----
  for (int idx = tid; idx < 450; idx += 256) {
    int t = idx / 25, j = idx % 25;
#pragma unroll
    for (int p = 0; p < 6; p++) {
      const float* X = (p < 3) ? sfv : sbev;
      const float* W_ = sW + (p % 3) * 625;
      float acc = sB[(p % 3) * 25 + j];
#pragma unroll
      for (int i = 0; i < 25; i++) acc = fmaf(X[t * 25 + i], W_[j * 25 + i], acc);
      pr[p][idx] = acc;
    }
  }
  __syncthreads();

  // ---- attention (both mhsa): row = (head, token), 90 rows ----
  const float rs5 = 0.44721359549995793f;  // 1/sqrt(5)
  if (tid < 90) {
    int hh = tid / 18, t = tid % 18;
#pragma unroll
    for (int m = 0; m < 2; m++) {
      const float* q = pr[m == 0 ? 0 : 3];  // m0: q from fv; m1: q from bev
      const float* k = pr[m == 0 ? 4 : 1];  // m0: k from bev; m1: k from fv
      const float* v = pr[m == 0 ? 2 : 5];  // m0: v from fv; m1: v from bev
      float p_[18];
      float mx = -1e30f;
#pragma unroll
      for (int ss = 0; ss < 18; ss++) {
        float sc = 0.f;
#pragma unroll
        for (int d = 0; d < 5; d++)
          sc = fmaf(q[t * 25 + hh * 5 + d], k[ss * 25 + hh * 5 + d], sc);
        sc *= rs5;
        p_[ss] = sc;
        mx = fmaxf(mx, sc);
      }
      float sm = 0.f;
#pragma unroll
      for (int ss = 0; ss < 18; ss++) {
        p_[ss] = expf(p_[ss] - mx);
        sm += p_[ss];
      }
      float inv = 1.f / sm;
#pragma unroll
      for (int d = 0; d < 5; d++) {
        float a = 0.f;
#pragma unroll
        for (int ss = 0; ss < 18; ss++)
          a = fmaf(p_[ss], v[ss * 25 + hh * 5 + d], a);
        av[m][t * 25 + hh * 5 + d] = a * inv;
      }
    }
  }
  __syncthreads();

  // ---- out-proj + residual (Wf from LDS) ----
  for (int idx = tid; idx < 450; idx += 256) {
    int t = idx / 25, j = idx % 25;
    float s1 = sB[75 + j] + sbev[idx];  // x1 residual = bev (feat1)
    float s2 = sB[75 + j] + sfv[idx];   // x2 residual = fv
#pragma unroll
    for (int i = 0; i < 25; i++) {
      float wv = sW[1875 + j * 25 + i];
      s1 = fmaf(av[0][t * 25 + i], wv, s1);
      s2 = fmaf(av[1][t * 25 + i], wv, s2);
    }
    xx[0][idx] = s1;
    xx[1][idx] = s2;
  }
  __syncthreads();

  // ---- conv 36->18, 3x3, pad 1 on 5x5 ----
  for (int idx = tid; idx < 450; idx += 256) {
    int co = idx / 25, pos = idx % 25, pi = pos / 5, pj = pos % 5;
    float acc = conv_b[co];
    for (int ci = 0; ci < 36; ci++) {
      const float* xc = (ci < 18) ? &xx[0][ci * 25] : &xx[1][(ci - 18) * 25];
      const float* wp = conv_w + ((size_t)co * 36 + ci) * 9;
#pragma unroll
      for (int dh = 0; dh < 3; dh++) {
        int rr = pi + dh - 1;
        if ((unsigned)rr < 5u) {
#pragma unroll
          for (int dw = 0; dw < 3; dw++) {
            int cc = pj + dw - 1;
            if ((unsigned)cc < 5u) acc = fmaf(xc[rr * 5 + cc], wp[dh * 3 + dw], acc);
          }
        }
      }
    }
    hid[idx] = acc;
  }
  __syncthreads();

  // ---- fc1 (225 x 450) + relu: thread t owns output o=t; wt_fc1[i][o] is
  // coalesced across lanes; 4 partial accumulators break the FMA chain ----
  if (tid < 225) {
    int o = tid;
    float a0 = fc1_b[o], a1 = 0.f, a2 = 0.f, a3 = 0.f;
    int i = 0;
    for (; i + 4 <= 448; i += 4) {
      a0 = fmaf(hid[i], wt_fc1[(size_t)i * 256 + o], a0);
      a1 = fmaf(hid[i + 1], wt_fc1[(size_t)(i + 1) * 256 + o], a1);
      a2 = fmaf(hid[i + 2], wt_fc1[(size_t)(i + 2) * 256 + o], a2);
      a3 = fmaf(hid[i + 3], wt_fc1[(size_t)(i + 3) * 256 + o], a3);
    }
    for (; i < 450; i++) a0 = fmaf(hid[i], wt_fc1[(size_t)i * 256 + o], a0);
    h1r[o] = fmaxf((a0 + a1) + (a2 + a3), 0.f);
  }
  __syncthreads();

  // ---- fc2 (3 x 225): wave w computes output w via shuffle reduction ----
  int wave = tid >> 6, lane = tid & 63;
  if (wave < 3) {
    const float* wr = fc2_w + (size_t)wave * 225;
    float p = 0.f;
#pragma unroll
    for (int k = 0; k < 4; k++) {
      int i = lane + k * 64;
      if (i < 225) p = fmaf(h1r[i], wr[i], p);
    }
#pragma unroll
    for (int m = 32; m >= 1; m >>= 1) p += __shfl_xor(p, m);
    if (lane == 0) lg[wave] = p + fc2_b[wave];
  }
  __syncthreads();

  // ---- argmax + softmax ----
  if (tid == 0) {
    float l0 = lg[0], l1 = lg[1], l2 = lg[2];
    int arg = 0;
    float bm = l0;
    if (l1 > bm) { arg = 1; bm = l1; }
    if (l2 > bm) { arg = 2; bm = l2; }
    float m = fmaxf(l0, fmaxf(l1, l2));
    float e0 = expf(l0 - m), e1 = expf(l1 - m), e2 = expf(l2 - m);
    float inv = 1.f / (e0 + e1 + e2);
    out[rid] = (float)(arg + 1);
    float* sc = out + 2048 + (size_t)rid * 3;
    sc[0] = e0 * inv;
    sc[1] = e1 * inv;
    sc[2] = e2 * inv;
  }
}

extern "C" void kernel_launch(void* const* d_in, const int* in_sizes, int n_in,
                              void* d_out, int out_size, void* d_ws, size_t ws_size,
                              hipStream_t stream) {
  const float* feat_fv = (const float*)d_in[0];
  const float* feat_bev = (const float*)d_in[1];
  const float* rois = (const float*)d_in[2];
  const float* fv_w1 = (const float*)d_in[3];
  const float* fv_b1 = (const float*)d_in[4];
  const float* fv_gamma = (const float*)d_in[5];
  const float* fv_beta = (const float*)d_in[6];
  const float* fv_mean = (const float*)d_in[7];
  const float* fv_var = (const float*)d_in[8];
  const float* fv_w2 = (const float*)d_in[9];
  const float* fv_b2 = (const float*)d_in[10];
  const float* bev_w1 = (const float*)d_in[11];
  const float* bev_b1 = (const float*)d_in[12];
  const float* bev_gamma = (const float*)d_in[13];
  const float* bev_beta = (const float*)d_in[14];
  const float* bev_mean = (const float*)d_in[15];
  const float* bev_var = (const float*)d_in[16];
  const float* bev_w2 = (const float*)d_in[17];
  const float* bev_b2 = (const float*)d_in[18];
  const float* Wq = (const float*)d_in[19];
  const float* bq = (const float*)d_in[20];
  const float* Wk = (const float*)d_in[21];
  const float* bk = (const float*)d_in[22];
  const float* Wv = (const float*)d_in[23];
  const float* bv = (const float*)d_in[24];
  const float* Wf = (const float*)d_in[25];
  const float* bf = (const float*)d_in[26];
  const float* conv_w = (const float*)d_in[27];
  const float* conv_b = (const float*)d_in[28];
  const float* fc1_w = (const float*)d_in[29];
  const float* fc1_b = (const float*)d_in[30];
  const float* fc2_w = (const float*)d_in[31];
  const float* fc2_b = (const float*)d_in[32];

  float* ws = (float*)d_ws;
  float* ffv = ws;                       // 2*18*64*512  = 1,179,648 floats
  float* fbev = ffv + 1179648;           // 2*18*200*176 = 1,267,200 floats
  float* wt_fv = fbev + 1267200;         // 128*9*18     = 20,736
  float* wt_bev = wt_fv + 20736;         // 512*9*18     = 82,944
  float* wt_fc1 = wt_bev + 82944;        // 450*256      = 115,200
  // total ~10.7 MB

  transpose_w_kernel<<<(18 * 128 * 9 + 255) / 256, 256, 0, stream>>>(fv_w1, wt_fv, 128);
  transpose_w_kernel<<<(18 * 512 * 9 + 255) / 256, 256, 0, stream>>>(bev_w1, wt_bev, 512);
  transpose_fc1_kernel<<<(225 * 450 + 255) / 256, 256, 0, stream>>>(fc1_w, wt_fc1);

  pre_kernel<16><<<dim3(512 / 64, 64, 2), 512, 0, stream>>>(
      feat_fv, wt_fv, fv_b1, fv_gamma, fv_beta, fv_mean, fv_var, fv_w2, fv_b2,
      ffv, 64, 512);
  pre_kernel<64><<<dim3((176 + 63) / 64, 200, 2), 512, 0, stream>>>(
      feat_bev, wt_bev, bev_b1, bev_gamma, bev_beta, bev_mean, bev_var, bev_w2,
      bev_b2, fbev, 200, 176);

  classifier_kernel<<<2048, 256, 0, stream>>>(
      ffv, fbev, rois, Wq, bq, Wk, bk, Wv, bv, Wf, bf, conv_w, conv_b, wt_fc1,
      fc1_b, fc2_w, fc2_b, (float*)d_out);
}

// Round 6
// 450.828 us; speedup vs baseline: 2.1813x; 2.1813x over previous
//
#include <hip/hip_runtime.h>
#include <math.h>

// ---------------- weight transpose: w[18][C][3][3] -> wt[C][9][18] ----------------
__global__ void transpose_w_kernel(const float* __restrict__ w, float* __restrict__ wt, int C) {
  int idx = blockIdx.x * blockDim.x + threadIdx.x;
  int total = 18 * C * 9;
  if (idx >= total) return;
  int co = idx / (C * 9);
  int rem = idx % (C * 9);
  int ci = rem / 9;
  int tap = rem % 9;
  wt[(ci * 9 + tap) * 18 + co] = w[idx];
}

// ---------------- fc1 transpose: fc1_w[225][450] -> wt[450][256] (padded) ----------------
__global__ void transpose_fc1_kernel(const float* __restrict__ w, float* __restrict__ wt) {
  int idx = blockIdx.x * blockDim.x + threadIdx.x;
  if (idx >= 225 * 450) return;
  int o = idx / 450;
  int i = idx % 450;
  wt[i * 256 + o] = w[idx];
}

// ------------- merged fused conv3x3 + BN + relu + conv1x1 (fv + bev in one grid) ------------
// Inner loop is the round-4 shape EXACTLY (54-weight row batches -> s_load scalar
// weights + v_fma with SGPR operand; do not restructure). Blocks 0..1199 = bev
// (longest-first), 1200..2223 = fv. All per-block params are blockIdx-derived ->
// wave-uniform -> scalar address chains preserved.
__global__ __launch_bounds__(256) void pre_merged_kernel(
    const float* __restrict__ xF, const float* __restrict__ wtF,
    const float* __restrict__ b1F, const float* __restrict__ gF,
    const float* __restrict__ beF, const float* __restrict__ muF,
    const float* __restrict__ vF, const float* __restrict__ w2F,
    const float* __restrict__ b2F, float* __restrict__ outF,
    const float* __restrict__ xB, const float* __restrict__ wtB,
    const float* __restrict__ b1B, const float* __restrict__ gB,
    const float* __restrict__ beB, const float* __restrict__ muB,
    const float* __restrict__ vB, const float* __restrict__ w2B,
    const float* __restrict__ b2B, float* __restrict__ outB) {
  int flat = blockIdx.x;
  const float *x, *wt, *b1, *gamma, *beta, *mean, *var, *w2, *b2;
  float* out;
  int H, W, cs, xt, h, b;
  if (flat < 1200) {  // bev: (3 xtiles, 200 h, 2 b), C=512, cs=128
    xt = flat % 3; h = (flat / 3) % 200; b = flat / 600;
    x = xB; wt = wtB; b1 = b1B; gamma = gB; beta = beB; mean = muB; var = vB;
    w2 = w2B; b2 = b2B; out = outB;
    H = 200; W = 176; cs = 128;
  } else {            // fv: (8 xtiles, 64 h, 2 b), C=128, cs=32
    int f = flat - 1200;
    xt = f & 7; h = (f >> 3) & 63; b = f >> 9;
    x = xF; wt = wtF; b1 = b1F; gamma = gF; beta = beF; mean = muF; var = vF;
    w2 = w2F; b2 = b2F; out = outF;
    H = 64; W = 512; cs = 32;
  }

  int tid = threadIdx.x;
  int pixel = tid & 63;
  int split = __builtin_amdgcn_readfirstlane(tid >> 6);  // wave-uniform -> SGPR
  int w = xt * 64 + pixel;
  bool active = (w < W);

  float acc[18];
#pragma unroll
  for (int i = 0; i < 18; i++) acc[i] = 0.f;

  const float* xb = x + (size_t)b * (cs * 4) * H * W;
  int ci0 = split * cs;
  for (int ci = 0; ci < cs; ci++) {
    const float* plane = xb + (size_t)(ci0 + ci) * H * W;
#pragma unroll
    for (int dh = 0; dh < 3; dh++) {
      int r = h + dh - 1;
      if ((unsigned)r < (unsigned)H) {
        const float* row = plane + (size_t)r * W;
        float v0 = (active && w >= 1) ? row[w - 1] : 0.f;
        float v1 = active ? row[w] : 0.f;
        float v2 = (active && w + 1 < W) ? row[w + 1] : 0.f;
        const float* wp = wt + ((size_t)(ci0 + ci) * 9 + dh * 3) * 18;  // scalar addr
#pragma unroll
        for (int co = 0; co < 18; co++) acc[co] = fmaf(v0, wp[co], acc[co]);
#pragma unroll
        for (int co = 0; co < 18; co++) acc[co] = fmaf(v1, wp[18 + co], acc[co]);
#pragma unroll
        for (int co = 0; co < 18; co++) acc[co] = fmaf(v2, wp[36 + co], acc[co]);
      }
    }
  }

  __shared__ float red[3][64][19];  // pad 19: conflict-free across pixel index
  if (split > 0) {
#pragma unroll
    for (int co = 0; co < 18; co++) red[split - 1][pixel][co] = acc[co];
  }
  __syncthreads();
  if (split == 0 && active) {
#pragma unroll
    for (int s = 0; s < 3; s++)
#pragma unroll
      for (int co = 0; co < 18; co++) acc[co] += red[s][pixel][co];
    float y[18];
#pragma unroll
    for (int co = 0; co < 18; co++) {
      float sc = gamma[co] / sqrtf(var[co] + 1e-3f);
      y[co] = fmaxf((acc[co] + b1[co] - mean[co]) * sc + beta[co], 0.f);
    }
    size_t obase = (size_t)b * 18 * H * W + (size_t)h * W + w;
#pragma unroll
    for (int co2 = 0; co2 < 18; co2++) {
      float s2 = b2[co2];
#pragma unroll
      for (int c = 0; c < 18; c++) s2 = fmaf(y[c], w2[co2 * 18 + c], s2);
      out[obase + (size_t)co2 * H * W] = s2;
    }
  }
}

// ------------- per-ROI classifier: one 256-thread block (4 waves) per ROI -------------
__global__ __launch_bounds__(256) void classifier_kernel(
    const float* __restrict__ ffv, const float* __restrict__ fbev,
    const float* __restrict__ rois, const float* __restrict__ Wq,
    const float* __restrict__ bq, const float* __restrict__ Wk,
    const float* __restrict__ bk, const float* __restrict__ Wv,
    const float* __restrict__ bv, const float* __restrict__ Wf,
    const float* __restrict__ bf, const float* __restrict__ conv_w,
    const float* __restrict__ conv_b, const float* __restrict__ wt_fc1,
    const float* __restrict__ fc1_b, const float* __restrict__ fc2_w,
    const float* __restrict__ fc2_b, float* __restrict__ out) {
  int rid = blockIdx.x;
  int b = rid >> 10;
  int tid = threadIdx.x;

  __shared__ float sW[2500];           // Wq | Wk | Wv | Wf (625 each)
  __shared__ float sB[100];            // bq | bk | bv | bf (25 each)
  __shared__ float sfv[450], sbev[450];
  __shared__ float pr[6][450];         // qf kf vf qb kb vb
  __shared__ float av[2][450];
  __shared__ float xx[2][450];
  __shared__ float hid[450];
  __shared__ float h1r[225];
  __shared__ float lg[3];
  __shared__ int c_ixf[25], c_iyf[25], c_vf[25];
  __shared__ int c_ixb[25], c_iyb[25], c_vb[25];

  // ---- stage projection weights + biases into LDS ----
  for (int t = tid; t < 625; t += 256) {
    sW[t] = Wq[t];
    sW[625 + t] = Wk[t];
    sW[1250 + t] = Wv[t];
    sW[1875 + t] = Wf[t];
  }
  if (tid < 25) {
    sB[tid] = bq[tid];
    sB[25 + tid] = bk[tid];
    sB[50 + tid] = bv[tid];
    sB[75 + tid] = bf[tid];
  }

  // ---- box + grids coords (double to match np f64 ref) ----
  if (tid < 25) {
    const float* roi = rois + (size_t)rid * 7;
    double x0 = roi[0], y0 = roi[1], z0 = roi[2];
    double dx = roi[3], dy = roi[4], dz = roi[5], th = roi[6];
    double c = cos(th), s = sin(th);
    double half1 = (dy * c + dx * s) / 2.0;
    double half2 = (dy * s + dx * c) / 2.0;
    double bx1 = x0 - half1, bx2 = x0 + half1;
    double by1 = y0 - half2, by2 = y0 + half2;
    double bz1 = z0 - dz / 2.0, bz2 = z0 + dz / 2.0;
    int i = tid / 5, j = tid % 5;
    double ti = i * 0.25, tj = j * 0.25;
    // fv: feat (18, 64, 512)
    double gz = bz1 + ti * (bz2 - bz1);
    gz = (gz + 1.0) / 2.0;
    double gx = bx1 + tj * (bx2 - bx1);
    gx = (gx - 35.2) / 35.2;
    double ixf = rint((gz + 1.0) * 0.5 * 511.0);
    double iyf = rint((gx + 1.0) * 0.5 * 63.0);
    c_vf[tid] = (ixf >= 0.0) && (ixf <= 511.0) && (iyf >= 0.0) && (iyf <= 63.0);
    c_ixf[tid] = (int)fmin(fmax(ixf, 0.0), 511.0);
    c_iyf[tid] = (int)fmin(fmax(iyf, 0.0), 63.0);
    // bev: feat (18, 200, 176)
    double gzb = (by1 + ti * (by2 - by1)) / 40.0;
    double ixb = rint((gzb + 1.0) * 0.5 * 175.0);
    double iyb = rint((gx + 1.0) * 0.5 * 199.0);
    c_vb[tid] = (ixb >= 0.0) && (ixb <= 175.0) && (iyb >= 0.0) && (iyb <= 199.0);
    c_ixb[tid] = (int)fmin(fmax(ixb, 0.0), 175.0);
    c_iyb[tid] = (int)fmin(fmax(iyb, 0.0), 199.0);
  }
  __syncthreads();

  // ---- gather: 900 items (450 fv + 450 bev) across 256 threads ----
  {
    const float* fvb = ffv + (size_t)b * 18 * 64 * 512;
    const float* bvb = fbev + (size_t)b * 18 * 200 * 176;
    for (int item = tid; item < 900; item += 256) {
      if (item < 450) {
        int ch = item / 25, pos = item % 25;
        sfv[item] = c_vf[pos] ? fvb[((size_t)ch * 64 + c_iyf[pos]) * 512 + c_ixf[pos]] : 0.f;
      } else {
        int it = item - 450;
        int ch = it / 25, pos = it % 25;
        sbev[it] = c_vb[pos] ? bvb[((size_t)ch * 200 + c_iyb[pos]) * 176 + c_ixb[pos]] : 0.f;
      }
    }
  }
  __syncthreads();

  // ---- 6 projections: {fv,bev} x {Wq,Wk,Wv} (weights from LDS) ----
  for (int idx = tid; idx < 450; idx += 256) {
    int t = idx / 25, j = idx % 25;
#pragma unroll
    for (int p = 0; p < 6; p++) {
      const float* X = (p < 3) ? sfv : sbev;
      const float* W_ = sW + (p % 3) * 625;
      float acc = sB[(p % 3) * 25 + j];
#pragma unroll
      for (int i = 0; i < 25; i++) acc = fmaf(X[t * 25 + i], W_[j * 25 + i], acc);
      pr[p][idx] = acc;
    }
  }
  __syncthreads();

  // ---- attention (both mhsa): row = (head, token), 90 rows ----
  const float rs5 = 0.44721359549995793f;  // 1/sqrt(5)
  if (tid < 90) {
    int hh = tid / 18, t = tid % 18;
#pragma unroll
    for (int m = 0; m < 2; m++) {
      const float* q = pr[m == 0 ? 0 : 3];  // m0: q from fv; m1: q from bev
      const float* k = pr[m == 0 ? 4 : 1];  // m0: k from bev; m1: k from fv
      const float* v = pr[m == 0 ? 2 : 5];  // m0: v from fv; m1: v from bev
      float p_[18];
      float mx = -1e30f;
#pragma unroll
      for (int ss = 0; ss < 18; ss++) {
        float sc = 0.f;
#pragma unroll
        for (int d = 0; d < 5; d++)
          sc = fmaf(q[t * 25 + hh * 5 + d], k[ss * 25 + hh * 5 + d], sc);
        sc *= rs5;
        p_[ss] = sc;
        mx = fmaxf(mx, sc);
      }
      float sm = 0.f;
#pragma unroll
      for (int ss = 0; ss < 18; ss++) {
        p_[ss] = expf(p_[ss] - mx);
        sm += p_[ss];
      }
      float inv = 1.f / sm;
#pragma unroll
      for (int d = 0; d < 5; d++) {
        float a = 0.f;
#pragma unroll
        for (int ss = 0; ss < 18; ss++)
          a = fmaf(p_[ss], v[ss * 25 + hh * 5 + d], a);
        av[m][t * 25 + hh * 5 + d] = a * inv;
      }
    }
  }
  __syncthreads();

  // ---- out-proj + residual (Wf from LDS) ----
  for (int idx = tid; idx < 450; idx += 256) {
    int t = idx / 25, j = idx % 25;
    float s1 = sB[75 + j] + sbev[idx];  // x1 residual = bev (feat1)
    float s2 = sB[75 + j] + sfv[idx];   // x2 residual = fv
#pragma unroll
    for (int i = 0; i < 25; i++) {
      float wv = sW[1875 + j * 25 + i];
      s1 = fmaf(av[0][t * 25 + i], wv, s1);
      s2 = fmaf(av[1][t * 25 + i], wv, s2);
    }
    xx[0][idx] = s1;
    xx[1][idx] = s2;
  }
  __syncthreads();

  // ---- conv 36->18, 3x3, pad 1 on 5x5 ----
  for (int idx = tid; idx < 450; idx += 256) {
    int co = idx / 25, pos = idx % 25, pi = pos / 5, pj = pos % 5;
    float acc = conv_b[co];
    for (int ci = 0; ci < 36; ci++) {
      const float* xc = (ci < 18) ? &xx[0][ci * 25] : &xx[1][(ci - 18) * 25];
      const float* wp = conv_w + ((size_t)co * 36 + ci) * 9;
#pragma unroll
      for (int dh = 0; dh < 3; dh++) {
        int rr = pi + dh - 1;
        if ((unsigned)rr < 5u) {
#pragma unroll
          for (int dw = 0; dw < 3; dw++) {
            int cc = pj + dw - 1;
            if ((unsigned)cc < 5u) acc = fmaf(xc[rr * 5 + cc], wp[dh * 3 + dw], acc);
          }
        }
      }
    }
    hid[idx] = acc;
  }
  __syncthreads();

  // ---- fc1 (225 x 450) + relu: thread t owns output o=t; wt_fc1[i][o] is
  // coalesced across lanes; 4 partial accumulators break the FMA chain ----
  if (tid < 225) {
    int o = tid;
    float a0 = fc1_b[o], a1 = 0.f, a2 = 0.f, a3 = 0.f;
    int i = 0;
    for (; i + 4 <= 448; i += 4) {
      a0 = fmaf(hid[i], wt_fc1[(size_t)i * 256 + o], a0);
      a1 = fmaf(hid[i + 1], wt_fc1[(size_t)(i + 1) * 256 + o], a1);
      a2 = fmaf(hid[i + 2], wt_fc1[(size_t)(i + 2) * 256 + o], a2);
      a3 = fmaf(hid[i + 3], wt_fc1[(size_t)(i + 3) * 256 + o], a3);
    }
    for (; i < 450; i++) a0 = fmaf(hid[i], wt_fc1[(size_t)i * 256 + o], a0);
    h1r[o] = fmaxf((a0 + a1) + (a2 + a3), 0.f);
  }
  __syncthreads();

  // ---- fc2 (3 x 225): wave w computes output w via shuffle reduction ----
  int wave = tid >> 6, lane = tid & 63;
  if (wave < 3) {
    const float* wr = fc2_w + (size_t)wave * 225;
    float p = 0.f;
#pragma unroll
    for (int k = 0; k < 4; k++) {
      int i = lane + k * 64;
      if (i < 225) p = fmaf(h1r[i], wr[i], p);
    }
#pragma unroll
    for (int m = 32; m >= 1; m >>= 1) p += __shfl_xor(p, m);
    if (lane == 0) lg[wave] = p + fc2_b[wave];
  }
  __syncthreads();

  // ---- argmax + softmax ----
  if (tid == 0) {
    float l0 = lg[0], l1 = lg[1], l2 = lg[2];
    int arg = 0;
    float bm = l0;
    if (l1 > bm) { arg = 1; bm = l1; }
    if (l2 > bm) { arg = 2; bm = l2; }
    float m = fmaxf(l0, fmaxf(l1, l2));
    float e0 = expf(l0 - m), e1 = expf(l1 - m), e2 = expf(l2 - m);
    float inv = 1.f / (e0 + e1 + e2);
    out[rid] = (float)(arg + 1);
    float* sc = out + 2048 + (size_t)rid * 3;
    sc[0] = e0 * inv;
    sc[1] = e1 * inv;
    sc[2] = e2 * inv;
  }
}

extern "C" void kernel_launch(void* const* d_in, const int* in_sizes, int n_in,
                              void* d_out, int out_size, void* d_ws, size_t ws_size,
                              hipStream_t stream) {
  const float* feat_fv = (const float*)d_in[0];
  const float* feat_bev = (const float*)d_in[1];
  const float* rois = (const float*)d_in[2];
  const float* fv_w1 = (const float*)d_in[3];
  const float* fv_b1 = (const float*)d_in[4];
  const float* fv_gamma = (const float*)d_in[5];
  const float* fv_beta = (const float*)d_in[6];
  const float* fv_mean = (const float*)d_in[7];
  const float* fv_var = (const float*)d_in[8];
  const float* fv_w2 = (const float*)d_in[9];
  const float* fv_b2 = (const float*)d_in[10];
  const float* bev_w1 = (const float*)d_in[11];
  const float* bev_b1 = (const float*)d_in[12];
  const float* bev_gamma = (const float*)d_in[13];
  const float* bev_beta = (const float*)d_in[14];
  const float* bev_mean = (const float*)d_in[15];
  const float* bev_var = (const float*)d_in[16];
  const float* bev_w2 = (const float*)d_in[17];
  const float* bev_b2 = (const float*)d_in[18];
  const float* Wq = (const float*)d_in[19];
  const float* bq = (const float*)d_in[20];
  const float* Wk = (const float*)d_in[21];
  const float* bk = (const float*)d_in[22];
  const float* Wv = (const float*)d_in[23];
  const float* bv = (const float*)d_in[24];
  const float* Wf = (const float*)d_in[25];
  const float* bf = (const float*)d_in[26];
  const float* conv_w = (const float*)d_in[27];
  const float* conv_b = (const float*)d_in[28];
  const float* fc1_w = (const float*)d_in[29];
  const float* fc1_b = (const float*)d_in[30];
  const float* fc2_w = (const float*)d_in[31];
  const float* fc2_b = (const float*)d_in[32];

  float* ws = (float*)d_ws;
  float* ffv = ws;                       // 2*18*64*512  = 1,179,648 floats
  float* fbev = ffv + 1179648;           // 2*18*200*176 = 1,267,200 floats
  float* wt_fv = fbev + 1267200;         // 128*9*18     = 20,736
  float* wt_bev = wt_fv + 20736;         // 512*9*18     = 82,944
  float* wt_fc1 = wt_bev + 82944;        // 450*256      = 115,200
  // total ~10.7 MB

  transpose_w_kernel<<<(18 * 128 * 9 + 255) / 256, 256, 0, stream>>>(fv_w1, wt_fv, 128);
  transpose_w_kernel<<<(18 * 512 * 9 + 255) / 256, 256, 0, stream>>>(bev_w1, wt_bev, 512);
  transpose_fc1_kernel<<<(225 * 450 + 255) / 256, 256, 0, stream>>>(fc1_w, wt_fc1);

  // merged pre: blocks [0,1200) = bev, [1200,2224) = fv
  pre_merged_kernel<<<2224, 256, 0, stream>>>(
      feat_fv, wt_fv, fv_b1, fv_gamma, fv_beta, fv_mean, fv_var, fv_w2, fv_b2, ffv,
      feat_bev, wt_bev, bev_b1, bev_gamma, bev_beta, bev_mean, bev_var, bev_w2, bev_b2, fbev);

  classifier_kernel<<<2048, 256, 0, stream>>>(
      ffv, fbev, rois, Wq, bq, Wk, bk, Wv, bv, Wf, bf, conv_w, conv_b, wt_fc1,
      fc1_b, fc2_w, fc2_b, (float*)d_out);
}